// Round 1
// baseline (194.615 us; speedup 1.0000x reference)
//
#include <hip/hip_runtime.h>
#include <math.h>

// Problem constants (match reference)
#define Bn 2
#define Nn 512
#define Cn 151
#define Dn 4096
#define W_IMG 800.0f
#define H_IMG 600.0f
#define SCORE_T 0.05f
#define NMS_T 0.5f
#define TOPN 300
#define DETMAX 100
#define BBOX_CLAMP 4.135166556742356f   // log(1000/16)

// Output layout (float32, concatenated flat in reference return order)
#define OFF_BOXES  ((size_t)0)
#define OFF_SCORES ((size_t)(Bn * Nn * 4))            // 4096
#define OFF_LABELS (OFF_SCORES + (size_t)(Bn * Nn))   // 5120
#define OFF_VALID  (OFF_LABELS + (size_t)(Bn * Nn))   // 6144
#define OFF_FEATS  (OFF_VALID + (size_t)(Bn * Nn))    // 7168

// ---------------------------------------------------------------------------
// k1: per-(b,n) softmax over C + box decode + clip.  grid = B*N, block = 256.
__global__ void k1_softmax_decode(const float* __restrict__ logits,
                                  const float* __restrict__ reg,
                                  const float* __restrict__ props,
                                  float* __restrict__ prob,
                                  float* __restrict__ boxes) {
  const int bn  = blockIdx.x;      // 0..B*N-1
  const int tid = threadIdx.x;     // 0..255, classes 0..150 active
  __shared__ float red[256];

  const float* lrow = logits + (size_t)bn * Cn;
  float x = (tid < Cn) ? lrow[tid] : -INFINITY;
  red[tid] = x;
  __syncthreads();
  for (int s = 128; s > 0; s >>= 1) {
    if (tid < s) red[tid] = fmaxf(red[tid], red[tid + s]);
    __syncthreads();
  }
  const float mx = red[0];
  __syncthreads();
  float e = (tid < Cn) ? expf(x - mx) : 0.0f;
  red[tid] = e;
  __syncthreads();
  for (int s = 128; s > 0; s >>= 1) {
    if (tid < s) red[tid] += red[tid + s];
    __syncthreads();
  }
  const float inv = 1.0f / red[0];

  if (tid < Cn) {
    prob[(size_t)bn * Cn + tid] = e * inv;

    // BoxCoder decode (maskrcnn-benchmark, TO_REMOVE=1)
    const float bx1 = props[bn * 4 + 0];
    const float by1 = props[bn * 4 + 1];
    const float bx2 = props[bn * 4 + 2];
    const float by2 = props[bn * 4 + 3];
    const float w  = bx2 - bx1 + 1.0f;
    const float h  = by2 - by1 + 1.0f;
    const float cx = bx1 + 0.5f * w;
    const float cy = by1 + 0.5f * h;
    const float* r = reg + ((size_t)bn * Cn + tid) * 4;
    const float dx = r[0] / 10.0f;
    const float dy = r[1] / 10.0f;
    const float dw = fminf(r[2] / 5.0f, BBOX_CLAMP);
    const float dh = fminf(r[3] / 5.0f, BBOX_CLAMP);
    const float pcx = dx * w + cx;
    const float pcy = dy * h + cy;
    const float pw  = expf(dw) * w;
    const float ph  = expf(dh) * h;
    float x1 = pcx - 0.5f * pw;
    float y1 = pcy - 0.5f * ph;
    float x2 = pcx + 0.5f * pw - 1.0f;
    float y2 = pcy + 0.5f * ph - 1.0f;
    // clip_to_image
    x1 = fminf(fmaxf(x1, 0.0f), W_IMG - 1.0f);
    x2 = fminf(fmaxf(x2, 0.0f), W_IMG - 1.0f);
    y1 = fminf(fmaxf(y1, 0.0f), H_IMG - 1.0f);
    y2 = fminf(fmaxf(y2, 0.0f), H_IMG - 1.0f);
    float* ob = boxes + ((size_t)bn * Cn + tid) * 4;
    ob[0] = x1; ob[1] = y1; ob[2] = x2; ob[3] = y2;
  }
}

// ---------------------------------------------------------------------------
// k2: per-(b,c) NMS.  grid = B*C, block = 256.
// Sort 512 (score,idx) pairs descending (ties: ascending idx == stable argsort
// of -scores), greedy-suppress with IoU>0.5 (+1 convention), cap cumsum<=300,
// scatter kept scores back to original proposal order into dist[B,N,C].
__global__ void k2_nms(const float* __restrict__ prob,
                       const float* __restrict__ boxes,
                       float* __restrict__ dist) {
  const int bc  = blockIdx.x;
  const int b   = bc / Cn;
  const int c   = bc % Cn;
  const int tid = threadIdx.x;

  if (c == 0) {   // background: always dropped
    for (int n = tid; n < Nn; n += 256) dist[((size_t)b * Nn + n) * Cn] = 0.0f;
    return;
  }

  __shared__ float ss[Nn];
  __shared__ int   si[Nn];
  __shared__ float sb[Nn][4];
  __shared__ int   sk[Nn];

  for (int n = tid; n < Nn; n += 256) {
    ss[n] = prob[((size_t)b * Nn + n) * Cn + c];
    si[n] = n;
  }
  __syncthreads();

  // Bitonic sort: "in order" == (score desc, idx asc)
  for (int k = 2; k <= Nn; k <<= 1) {
    for (int j = k >> 1; j > 0; j >>= 1) {
      for (int t = tid; t < Nn; t += 256) {
        const int ixj = t ^ j;
        if (ixj > t) {
          const bool up = ((t & k) == 0);
          const float s1 = ss[t], s2 = ss[ixj];
          const int   i1 = si[t], i2 = si[ixj];
          const bool inOrder = (s1 > s2) || (s1 == s2 && i1 < i2);
          if (up != inOrder) {
            ss[t] = s2; ss[ixj] = s1;
            si[t] = i2; si[ixj] = i1;
          }
        }
      }
      __syncthreads();
    }
  }

  // Load boxes in sorted order; init keep = (score > thresh)
  for (int t = tid; t < Nn; t += 256) {
    const int n = si[t];
    const float* bp = boxes + (((size_t)b * Nn + n) * Cn + c) * 4;
    sb[t][0] = bp[0]; sb[t][1] = bp[1]; sb[t][2] = bp[2]; sb[t][3] = bp[3];
    sk[t] = (ss[t] > SCORE_T) ? 1 : 0;
  }
  __syncthreads();

  // Greedy NMS; uniform scan skips dead iterations (no barrier cost there).
  int i = 0;
  while (true) {
    while (i < Nn && !sk[i]) ++i;   // uniform across block: sk stable here
    if (i >= Nn - 1) break;
    const float ax1 = sb[i][0], ay1 = sb[i][1], ax2 = sb[i][2], ay2 = sb[i][3];
    const float aarea = (ax2 - ax1 + 1.0f) * (ay2 - ay1 + 1.0f);
    for (int t = i + 1 + tid; t < Nn; t += 256) {
      if (sk[t]) {
        const float bx1 = sb[t][0], by1 = sb[t][1], bx2 = sb[t][2], by2 = sb[t][3];
        const float barea = (bx2 - bx1 + 1.0f) * (by2 - by1 + 1.0f);
        const float xx1 = fmaxf(ax1, bx1), yy1 = fmaxf(ay1, by1);
        const float xx2 = fminf(ax2, bx2), yy2 = fminf(ay2, by2);
        const float inter = fmaxf(xx2 - xx1 + 1.0f, 0.0f) * fmaxf(yy2 - yy1 + 1.0f, 0.0f);
        const float iou = inter / (aarea + barea - inter);
        if (iou > NMS_T) sk[t] = 0;
      }
    }
    __syncthreads();
    ++i;
  }
  __syncthreads();

  // post-NMS per-class top-300 (cumsum in sorted order)
  if (tid == 0) {
    int cnt = 0;
    for (int t = 0; t < Nn; ++t) {
      if (sk[t]) { ++cnt; if (cnt > TOPN) sk[t] = 0; }
    }
  }
  __syncthreads();

  // scatter kept scores back to original order
  for (int t = tid; t < Nn; t += 256) {
    const int n = si[t];
    dist[((size_t)b * Nn + n) * Cn + c] = sk[t] ? ss[t] : 0.0f;
  }
}

// ---------------------------------------------------------------------------
// k3: per-(b,n) argmax over C of dist (first-max index) + max score.
__global__ void k3_argmax(const float* __restrict__ dist,
                          float* __restrict__ scores_pre,
                          int* __restrict__ labels) {
  const int i = blockIdx.x * blockDim.x + threadIdx.x;
  if (i >= Bn * Nn) return;
  const float* d = dist + (size_t)i * Cn;
  float best = d[0];
  int   bl   = 0;
  for (int c = 1; c < Cn; ++c) {
    const float v = d[c];
    if (v > best) { best = v; bl = c; }   // strict > keeps first occurrence
  }
  scores_pre[i] = best;
  labels[i]     = bl;
}

// ---------------------------------------------------------------------------
// k4: per-image kth-largest threshold (detections_per_img cap). grid=B, blk=256.
__global__ void k4_thresh(const float* __restrict__ scores_pre,
                          float* __restrict__ thr) {
  const int b   = blockIdx.x;
  const int tid = threadIdx.x;
  __shared__ float v[Nn];
  __shared__ int   cr[256];

  int cnt = 0;
  for (int n = tid; n < Nn; n += 256) {
    const float s = scores_pre[b * Nn + n];
    v[n] = (s > 0.0f) ? s : -1.0f;
    if (s > 0.0f) ++cnt;
  }
  cr[tid] = cnt;
  __syncthreads();
  for (int s = 128; s > 0; s >>= 1) {
    if (tid < s) cr[tid] += cr[tid + s];
    __syncthreads();
  }

  // bitonic sort v descending (values only; ties value-identical)
  for (int k = 2; k <= Nn; k <<= 1) {
    for (int j = k >> 1; j > 0; j >>= 1) {
      for (int t = tid; t < Nn; t += 256) {
        const int ixj = t ^ j;
        if (ixj > t) {
          const bool up = ((t & k) == 0);
          const float a = v[t], b2 = v[ixj];
          const bool inOrder = (a > b2);
          if (up != inOrder && a != b2) { v[t] = b2; v[ixj] = a; }
        }
      }
      __syncthreads();
    }
  }
  if (tid == 0) {
    thr[b] = (cr[0] > DETMAX) ? v[DETMAX - 1] : -1.0f;
  }
}

// ---------------------------------------------------------------------------
// k5: per-(b,n) final boxes/scores/labels/valid.
__global__ void k5_final(const float* __restrict__ boxes,
                         const float* __restrict__ scores_pre,
                         const int* __restrict__ labels,
                         const float* __restrict__ thr,
                         float* __restrict__ out) {
  const int i = blockIdx.x * blockDim.x + threadIdx.x;
  if (i >= Bn * Nn) return;
  const int b = i / Nn;
  const float s  = scores_pre[i];
  const int  lab = labels[i];
  const bool valid = (s > 0.0f) && (s >= thr[b]);
  const float* bp = boxes + ((size_t)i * Cn + lab) * 4;
  float* ob = out + OFF_BOXES + (size_t)i * 4;
  ob[0] = valid ? bp[0] : 0.0f;
  ob[1] = valid ? bp[1] : 0.0f;
  ob[2] = valid ? bp[2] : 0.0f;
  ob[3] = valid ? bp[3] : 0.0f;
  out[OFF_SCORES + i] = valid ? s : 0.0f;
  out[OFF_LABELS + i] = valid ? (float)lab : 0.0f;
  out[OFF_VALID  + i] = valid ? 1.0f : 0.0f;
}

// ---------------------------------------------------------------------------
// k6: nms_features = features * det_valid. grid = B*N rows, block = 256, float4.
__global__ void k6_feats(const float* __restrict__ feats,
                         const float* __restrict__ valid,
                         float* __restrict__ out) {
  const int row = blockIdx.x;
  const float m = valid[row];
  const float4* fi = (const float4*)(feats + (size_t)row * Dn);
  float4* fo = (float4*)(out + (size_t)row * Dn);
  for (int t = threadIdx.x; t < Dn / 4; t += 256) {
    float4 x = fi[t];
    x.x *= m; x.y *= m; x.z *= m; x.w *= m;
    fo[t] = x;
  }
}

// ---------------------------------------------------------------------------
extern "C" void kernel_launch(void* const* d_in, const int* in_sizes, int n_in,
                              void* d_out, int out_size, void* d_ws, size_t ws_size,
                              hipStream_t stream) {
  const float* logits = (const float*)d_in[0];   // [B,N,C]
  const float* reg    = (const float*)d_in[1];   // [B,N,C*4]
  const float* props  = (const float*)d_in[2];   // [B,N,4]
  const float* feats  = (const float*)d_in[3];   // [B,N,D]
  float* out = (float*)d_out;

  // workspace carve-up (floats)
  float* ws        = (float*)d_ws;
  float* prob      = ws;                              // B*N*C   = 154624
  float* boxes     = prob + (size_t)Bn * Nn * Cn;     // B*N*C*4 = 618496
  float* dist      = boxes + (size_t)Bn * Nn * Cn * 4;// B*N*C   = 154624
  float* scores_pre= dist + (size_t)Bn * Nn * Cn;     // B*N     = 1024
  int*   labels    = (int*)(scores_pre + Bn * Nn);    // B*N
  float* thr       = (float*)(labels + Bn * Nn);      // B

  k1_softmax_decode<<<Bn * Nn, 256, 0, stream>>>(logits, reg, props, prob, boxes);
  k2_nms<<<Bn * Cn, 256, 0, stream>>>(prob, boxes, dist);
  k3_argmax<<<(Bn * Nn + 255) / 256, 256, 0, stream>>>(dist, scores_pre, labels);
  k4_thresh<<<Bn, 256, 0, stream>>>(scores_pre, thr);
  k5_final<<<(Bn * Nn + 255) / 256, 256, 0, stream>>>(boxes, scores_pre, labels, thr, out);
  k6_feats<<<Bn * Nn, 256, 0, stream>>>(feats, out + OFF_VALID, out + OFF_FEATS);
}

// Round 2
// 97.668 us; speedup vs baseline: 1.9926x; 1.9926x over previous
//
#include <hip/hip_runtime.h>
#include <math.h>

// Problem constants (match reference)
#define Bn 2
#define Nn 512
#define Cn 151
#define Dn 4096
#define W_IMG 800.0f
#define H_IMG 600.0f
#define SCORE_T 0.05f
#define NMS_T 0.5f
#define TOPN 300
#define DETMAX 100
#define BBOX_CLAMP 4.135166556742356f   // log(1000/16)

// Output layout (float32, concatenated flat in reference return order)
#define OFF_BOXES  ((size_t)0)
#define OFF_SCORES ((size_t)(Bn * Nn * 4))            // 4096
#define OFF_LABELS (OFF_SCORES + (size_t)(Bn * Nn))   // 5120
#define OFF_VALID  (OFF_LABELS + (size_t)(Bn * Nn))   // 6144
#define OFF_FEATS  (OFF_VALID + (size_t)(Bn * Nn))    // 7168

// ---------------------------------------------------------------------------
// kA: one WAVE per (b,n). Softmax over C (shuffle reductions, no barriers),
// box decode+clip for all C, write prob TRANSPOSED [B,C,N] for coalesced NMS
// loads, zero the packed argmax slots. grid = B*N/4 blocks x 256 (4 waves).
__global__ void kA_softmax_decode(const float* __restrict__ logits,
                                  const float* __restrict__ reg,
                                  const float* __restrict__ props,
                                  float* __restrict__ prob_t,
                                  float* __restrict__ boxes,
                                  unsigned long long* __restrict__ packed) {
  const int wave = threadIdx.x >> 6;
  const int lane = threadIdx.x & 63;
  const int bn = blockIdx.x * 4 + wave;     // 0..B*N-1
  const int b = bn >> 9;                    // /Nn
  const int n = bn & (Nn - 1);

  const float* lrow = logits + (size_t)bn * Cn;
  // C=151: lane covers c = lane, lane+64, lane+128
  const float l0 = lrow[lane];
  const float l1 = lrow[lane + 64];
  const float l2 = (lane + 128 < Cn) ? lrow[lane + 128] : -INFINITY;

  float mx = fmaxf(l0, fmaxf(l1, l2));
  #pragma unroll
  for (int o = 32; o > 0; o >>= 1) mx = fmaxf(mx, __shfl_xor(mx, o));

  const float e0 = expf(l0 - mx);
  const float e1 = expf(l1 - mx);
  const float e2 = (lane + 128 < Cn) ? expf(l2 - mx) : 0.0f;
  float sum = e0 + e1 + e2;
  #pragma unroll
  for (int o = 32; o > 0; o >>= 1) sum += __shfl_xor(sum, o);
  const float inv = 1.0f / sum;

  // prob_t[b][c][n]
  float* pt = prob_t + (size_t)b * Cn * Nn + n;
  pt[(size_t)lane * Nn] = e0 * inv;
  pt[(size_t)(lane + 64) * Nn] = e1 * inv;
  if (lane + 128 < Cn) pt[(size_t)(lane + 128) * Nn] = e2 * inv;

  // proposal geometry (wave-uniform)
  const float bx1 = props[bn * 4 + 0];
  const float by1 = props[bn * 4 + 1];
  const float bx2 = props[bn * 4 + 2];
  const float by2 = props[bn * 4 + 3];
  const float w = bx2 - bx1 + 1.0f;
  const float h = by2 - by1 + 1.0f;
  const float cx = bx1 + 0.5f * w;
  const float cy = by1 + 0.5f * h;

  #pragma unroll
  for (int rr = 0; rr < 3; ++rr) {
    const int c = lane + rr * 64;
    if (c < Cn) {
      const float* r = reg + ((size_t)bn * Cn + c) * 4;
      const float dx = r[0] * 0.1f;
      const float dy = r[1] * 0.1f;
      const float dw = fminf(r[2] * 0.2f, BBOX_CLAMP);
      const float dh = fminf(r[3] * 0.2f, BBOX_CLAMP);
      const float pcx = dx * w + cx;
      const float pcy = dy * h + cy;
      const float pw = expf(dw) * w;
      const float ph = expf(dh) * h;
      float x1 = pcx - 0.5f * pw;
      float y1 = pcy - 0.5f * ph;
      float x2 = pcx + 0.5f * pw - 1.0f;
      float y2 = pcy + 0.5f * ph - 1.0f;
      x1 = fminf(fmaxf(x1, 0.0f), W_IMG - 1.0f);
      x2 = fminf(fmaxf(x2, 0.0f), W_IMG - 1.0f);
      y1 = fminf(fmaxf(y1, 0.0f), H_IMG - 1.0f);
      y2 = fminf(fmaxf(y2, 0.0f), H_IMG - 1.0f);
      float* ob = boxes + ((size_t)bn * Cn + c) * 4;
      ob[0] = x1; ob[1] = y1; ob[2] = x2; ob[3] = y2;
    }
  }

  if (lane == 0) packed[bn] = 0ull;
}

// ---------------------------------------------------------------------------
// kB: one wave per (b,c). Compact valid (score > T) items, sort (score desc,
// idx asc), greedy NMS. Fast path M<=64 entirely in registers (shuffle rank
// sort + ballot suppression); exact LDS fallback for M>64. Kept items emit
// atomicMax of packed key (score_bits<<32 | Cn-c) -> per-proposal argmax.
__global__ void kB_nms(const float* __restrict__ prob_t,
                       const float* __restrict__ boxes,
                       unsigned long long* __restrict__ packed) {
  const int bc = blockIdx.x;
  const int b = bc / Cn;
  const int c = bc % Cn;
  const int lane = threadIdx.x;
  if (c == 0) return;   // background class dropped; packed stays 0

  __shared__ float ls[Nn];
  __shared__ int   ln[Nn];
  __shared__ float ss2[64];
  __shared__ int   sn2[64];
  __shared__ float fs[Nn];
  __shared__ int   fn[Nn];
  __shared__ float fb[Nn][4];
  __shared__ unsigned char kp[Nn];

  // compact valid items (order irrelevant: sort uses explicit (s,n) comparator)
  const float* col = prob_t + ((size_t)b * Cn + c) * Nn;
  int base = 0;
  #pragma unroll
  for (int j = 0; j < Nn / 64; ++j) {
    const int n = j * 64 + lane;
    const float s = col[n];
    const bool v = s > SCORE_T;
    const unsigned long long m = __ballot(v);
    if (v) {
      const int pos = base + __popcll(m & ((1ull << lane) - 1ull));
      ls[pos] = s; ln[pos] = n;
    }
    base += __popcll(m);
  }
  const int M = base;
  if (M == 0) return;
  __syncthreads();

  if (M <= 64) {
    // ---- register fast path ----
    float s = -1.0f; int n = -1;
    if (lane < M) { s = ls[lane]; n = ln[lane]; }
    int rank = 0;
    for (int j = 0; j < M; ++j) {
      const float sj = __shfl(s, j);
      const int nj = __shfl(n, j);
      if (lane < M) rank += (sj > s) || (sj == s && nj < n);
    }
    if (lane < M) { ss2[rank] = s; sn2[rank] = n; }
    __syncthreads();

    float sc = 0.0f; int sn = 0;
    float x1 = 0.0f, y1 = 0.0f, x2 = 0.0f, y2 = 0.0f;
    if (lane < M) {
      sc = ss2[lane]; sn = sn2[lane];
      const float4 bp = *(const float4*)(boxes + (((size_t)b * Nn + sn) * Cn + c) * 4);
      x1 = bp.x; y1 = bp.y; x2 = bp.z; y2 = bp.w;
    }
    const float area = (x2 - x1 + 1.0f) * (y2 - y1 + 1.0f);

    unsigned long long live = (M >= 64) ? ~0ull : ((1ull << M) - 1ull);
    int i = 0;
    while (i < 64) {
      const unsigned long long rem = live & (~0ull << i);
      if (!rem) break;
      i = __ffsll(rem) - 1;
      const float ax1 = __shfl(x1, i), ay1 = __shfl(y1, i);
      const float ax2 = __shfl(x2, i), ay2 = __shfl(y2, i);
      const float aarea = (ax2 - ax1 + 1.0f) * (ay2 - ay1 + 1.0f);
      const float xx1 = fmaxf(ax1, x1), yy1 = fmaxf(ay1, y1);
      const float xx2 = fminf(ax2, x2), yy2 = fminf(ay2, y2);
      const float inter = fmaxf(xx2 - xx1 + 1.0f, 0.0f) * fmaxf(yy2 - yy1 + 1.0f, 0.0f);
      const float iou = inter / (aarea + area - inter);
      const bool sup = (lane > i) && (lane < M) && ((live >> lane) & 1ull) && (iou > NMS_T);
      live &= ~__ballot(sup);
      ++i;
    }
    // M <= 64 < TOPN: top-300 cap can't bind
    if (lane < M && ((live >> lane) & 1ull)) {
      const unsigned long long key =
          ((unsigned long long)__float_as_uint(sc) << 32) | (unsigned int)(Cn - c);
      atomicMax(&packed[(size_t)b * Nn + sn], key);
    }
  } else {
    // ---- exact LDS fallback (M > 64, improbable) ----
    for (int i0 = lane; i0 < M; i0 += 64) {
      const float si = ls[i0]; const int ni = ln[i0];
      int r = 0;
      for (int j = 0; j < M; ++j) {
        const float sj = ls[j]; const int nj = ln[j];
        r += (sj > si) || (sj == si && nj < ni);
      }
      fs[r] = si; fn[r] = ni;
    }
    __syncthreads();
    for (int i0 = lane; i0 < M; i0 += 64) {
      const float4 bp = *(const float4*)(boxes + (((size_t)b * Nn + fn[i0]) * Cn + c) * 4);
      fb[i0][0] = bp.x; fb[i0][1] = bp.y; fb[i0][2] = bp.z; fb[i0][3] = bp.w;
      kp[i0] = 1;
    }
    __syncthreads();
    for (int i = 0; i < M; ++i) {
      if (!kp[i]) continue;                 // uniform: kp[i] stable here
      const float ax1 = fb[i][0], ay1 = fb[i][1], ax2 = fb[i][2], ay2 = fb[i][3];
      const float aarea = (ax2 - ax1 + 1.0f) * (ay2 - ay1 + 1.0f);
      for (int t = i + 1 + lane; t < M; t += 64) {
        if (kp[t]) {
          const float bx1 = fb[t][0], by1 = fb[t][1], bx2 = fb[t][2], by2 = fb[t][3];
          const float barea = (bx2 - bx1 + 1.0f) * (by2 - by1 + 1.0f);
          const float xx1 = fmaxf(ax1, bx1), yy1 = fmaxf(ay1, by1);
          const float xx2 = fminf(ax2, bx2), yy2 = fminf(ay2, by2);
          const float inter = fmaxf(xx2 - xx1 + 1.0f, 0.0f) * fmaxf(yy2 - yy1 + 1.0f, 0.0f);
          if (inter / (aarea + barea - inter) > NMS_T) kp[t] = 0;
        }
      }
      __syncthreads();
    }
    if (lane == 0) {
      int cnt = 0;
      for (int t = 0; t < M; ++t)
        if (kp[t]) { if (++cnt > TOPN) kp[t] = 0; }
    }
    __syncthreads();
    for (int t = lane; t < M; t += 64) {
      if (kp[t]) {
        const unsigned long long key =
            ((unsigned long long)__float_as_uint(fs[t]) << 32) | (unsigned int)(Cn - c);
        atomicMax(&packed[(size_t)b * Nn + fn[t]], key);
      }
    }
  }
}

// ---------------------------------------------------------------------------
// kC: one block per image (512 threads = 1 thread per proposal). Unpack
// (score,label), top-100 threshold via bitonic sort of 512 values, write
// boxes/scores/labels/valid outputs.
__global__ void kC_final(const unsigned long long* __restrict__ packed,
                         const float* __restrict__ boxes,
                         float* __restrict__ out) {
  const int b = blockIdx.x;
  const int n = threadIdx.x;        // 0..511
  __shared__ float v[Nn];
  __shared__ int wcnt[8];
  __shared__ float sThr;

  const unsigned long long p = packed[(size_t)b * Nn + n];
  const float s = __uint_as_float((unsigned int)(p >> 32));
  const int label = (p != 0ull) ? (Cn - (int)(p & 0xFFFFFFFFull)) : 0;
  const bool pos = (s > 0.0f);
  v[n] = pos ? s : -1.0f;

  // count positives (wave ballots -> LDS)
  const unsigned long long bal = __ballot(pos);
  if ((n & 63) == 0) wcnt[n >> 6] = __popcll(bal);
  __syncthreads();
  int num = 0;
  #pragma unroll
  for (int i = 0; i < 8; ++i) num += wcnt[i];

  // bitonic sort v descending (values only)
  for (int k = 2; k <= Nn; k <<= 1) {
    for (int j = k >> 1; j > 0; j >>= 1) {
      const int ixj = n ^ j;
      if (ixj > n) {
        const bool up = ((n & k) == 0);
        const float a = v[n], bb = v[ixj];
        if (up != (a > bb) && a != bb) { v[n] = bb; v[ixj] = a; }
      }
      __syncthreads();
    }
  }
  if (n == 0) sThr = (num > DETMAX) ? v[DETMAX - 1] : -1.0f;
  __syncthreads();

  const bool valid = pos && (s >= sThr);
  const int i = b * Nn + n;
  float4 ob = make_float4(0.0f, 0.0f, 0.0f, 0.0f);
  if (valid) ob = *(const float4*)(boxes + (((size_t)i) * Cn + label) * 4);
  *(float4*)(out + OFF_BOXES + (size_t)i * 4) = ob;
  out[OFF_SCORES + i] = valid ? s : 0.0f;
  out[OFF_LABELS + i] = valid ? (float)label : 0.0f;
  out[OFF_VALID + i] = valid ? 1.0f : 0.0f;
}

// ---------------------------------------------------------------------------
// kD: nms_features = features * det_valid. grid = B*N rows, block = 256, float4.
__global__ void kD_feats(const float* __restrict__ feats,
                         const float* __restrict__ valid,
                         float* __restrict__ out) {
  const int row = blockIdx.x;
  const float m = valid[row];
  const float4* fi = (const float4*)(feats + (size_t)row * Dn);
  float4* fo = (float4*)(out + (size_t)row * Dn);
  #pragma unroll 4
  for (int t = threadIdx.x; t < Dn / 4; t += 256) {
    float4 x = fi[t];
    x.x *= m; x.y *= m; x.z *= m; x.w *= m;
    fo[t] = x;
  }
}

// ---------------------------------------------------------------------------
extern "C" void kernel_launch(void* const* d_in, const int* in_sizes, int n_in,
                              void* d_out, int out_size, void* d_ws, size_t ws_size,
                              hipStream_t stream) {
  const float* logits = (const float*)d_in[0];   // [B,N,C]
  const float* reg    = (const float*)d_in[1];   // [B,N,C*4]
  const float* props  = (const float*)d_in[2];   // [B,N,4]
  const float* feats  = (const float*)d_in[3];   // [B,N,D]
  float* out = (float*)d_out;

  // workspace carve-up: packed (8B-aligned, first), prob_t, boxes
  unsigned long long* packed = (unsigned long long*)d_ws;          // B*N
  float* prob_t = (float*)(packed + Bn * Nn);                      // B*C*N
  float* boxes  = prob_t + (size_t)Bn * Cn * Nn;                   // B*N*C*4

  kA_softmax_decode<<<Bn * Nn / 4, 256, 0, stream>>>(logits, reg, props,
                                                     prob_t, boxes, packed);
  kB_nms<<<Bn * Cn, 64, 0, stream>>>(prob_t, boxes, packed);
  kC_final<<<Bn, Nn, 0, stream>>>(packed, boxes, out);
  kD_feats<<<Bn * Nn, 256, 0, stream>>>(feats, out + OFF_VALID, out + OFF_FEATS);
}

// Round 3
// 96.976 us; speedup vs baseline: 2.0068x; 1.0071x over previous
//
#include <hip/hip_runtime.h>
#include <math.h>

// Problem constants (match reference)
#define Bn 2
#define Nn 512
#define Cn 151
#define Dn 4096
#define W_IMG 800.0f
#define H_IMG 600.0f
#define SCORE_T 0.05f
#define NMS_T 0.5f
#define TOPN 300
#define DETMAX 100
#define BBOX_CLAMP 4.135166556742356f   // log(1000/16)

// Output layout (float32, concatenated flat in reference return order)
#define OFF_BOXES  ((size_t)0)
#define OFF_SCORES ((size_t)(Bn * Nn * 4))            // 4096
#define OFF_LABELS (OFF_SCORES + (size_t)(Bn * Nn))   // 5120
#define OFF_VALID  (OFF_LABELS + (size_t)(Bn * Nn))   // 6144
#define OFF_FEATS  (OFF_VALID + (size_t)(Bn * Nn))    // 7168

// ---------------------------------------------------------------------------
// Inline box decode + clip for one (proposal, class). Identical arithmetic to
// the reference BoxCoder (TO_REMOVE=1) + clip_to_image.
__device__ __forceinline__ float4 decode_clip(const float4 pr, const float4 rg) {
  const float w = pr.z - pr.x + 1.0f;
  const float h = pr.w - pr.y + 1.0f;
  const float cx = pr.x + 0.5f * w;
  const float cy = pr.y + 0.5f * h;
  const float dx = rg.x / 10.0f;
  const float dy = rg.y / 10.0f;
  const float dw = fminf(rg.z / 5.0f, BBOX_CLAMP);
  const float dh = fminf(rg.w / 5.0f, BBOX_CLAMP);
  const float pcx = dx * w + cx;
  const float pcy = dy * h + cy;
  const float pw = expf(dw) * w;
  const float ph = expf(dh) * h;
  float x1 = pcx - 0.5f * pw;
  float y1 = pcy - 0.5f * ph;
  float x2 = pcx + 0.5f * pw - 1.0f;
  float y2 = pcy + 0.5f * ph - 1.0f;
  x1 = fminf(fmaxf(x1, 0.0f), W_IMG - 1.0f);
  x2 = fminf(fmaxf(x2, 0.0f), W_IMG - 1.0f);
  y1 = fminf(fmaxf(y1, 0.0f), H_IMG - 1.0f);
  y2 = fminf(fmaxf(y2, 0.0f), H_IMG - 1.0f);
  return make_float4(x1, y1, x2, y2);
}

// ---------------------------------------------------------------------------
// kA: one WAVE per (b,n). Softmax over C (shuffle reductions, no barriers),
// write prob TRANSPOSED [B,C,N] for coalesced NMS loads, zero packed slots.
// grid = B*N/4 blocks x 256 (4 waves). No box decode here (done on demand).
__global__ void kA_softmax(const float* __restrict__ logits,
                           float* __restrict__ prob_t,
                           unsigned long long* __restrict__ packed) {
  const int wave = threadIdx.x >> 6;
  const int lane = threadIdx.x & 63;
  const int bn = blockIdx.x * 4 + wave;     // 0..B*N-1
  const int b = bn >> 9;                    // /Nn
  const int n = bn & (Nn - 1);

  const float* lrow = logits + (size_t)bn * Cn;
  const float l0 = lrow[lane];
  const float l1 = lrow[lane + 64];
  const float l2 = (lane + 128 < Cn) ? lrow[lane + 128] : -INFINITY;

  float mx = fmaxf(l0, fmaxf(l1, l2));
  #pragma unroll
  for (int o = 32; o > 0; o >>= 1) mx = fmaxf(mx, __shfl_xor(mx, o));

  const float e0 = expf(l0 - mx);
  const float e1 = expf(l1 - mx);
  const float e2 = (lane + 128 < Cn) ? expf(l2 - mx) : 0.0f;
  float sum = e0 + e1 + e2;
  #pragma unroll
  for (int o = 32; o > 0; o >>= 1) sum += __shfl_xor(sum, o);
  const float inv = 1.0f / sum;

  float* pt = prob_t + (size_t)b * Cn * Nn + n;
  pt[(size_t)lane * Nn] = e0 * inv;
  pt[(size_t)(lane + 64) * Nn] = e1 * inv;
  if (lane + 128 < Cn) pt[(size_t)(lane + 128) * Nn] = e2 * inv;

  if (lane == 0) packed[bn] = 0ull;
}

// ---------------------------------------------------------------------------
// kB: one wave per (b,c). Compact valid (score > T) items, sort (score desc,
// idx asc), decode boxes on demand for valid lanes, greedy NMS. Fast path
// M<=64 in registers (shuffle rank sort + ballot suppression); exact LDS
// fallback for M>64. Kept items emit atomicMax of packed key
// (score_bits<<32 | Cn-c) -> per-proposal argmax with first-index tiebreak.
__global__ void kB_nms(const float* __restrict__ prob_t,
                       const float* __restrict__ reg,
                       const float* __restrict__ props,
                       unsigned long long* __restrict__ packed) {
  const int bc = blockIdx.x;
  const int b = bc / Cn;
  const int c = bc % Cn;
  const int lane = threadIdx.x;
  if (c == 0) return;   // background class dropped; packed stays 0

  __shared__ float ls[Nn];
  __shared__ int   ln[Nn];
  __shared__ float ss2[64];
  __shared__ int   sn2[64];
  __shared__ float fs[Nn];
  __shared__ int   fn[Nn];
  __shared__ float fb[Nn][4];
  __shared__ unsigned char kp[Nn];

  // compact valid items (order irrelevant: sort uses explicit (s,n) comparator)
  const float* col = prob_t + ((size_t)b * Cn + c) * Nn;
  int base = 0;
  #pragma unroll
  for (int j = 0; j < Nn / 64; ++j) {
    const int n = j * 64 + lane;
    const float s = col[n];
    const bool v = s > SCORE_T;
    const unsigned long long m = __ballot(v);
    if (v) {
      const int pos = base + __popcll(m & ((1ull << lane) - 1ull));
      ls[pos] = s; ln[pos] = n;
    }
    base += __popcll(m);
  }
  const int M = base;
  if (M == 0) return;
  __syncthreads();

  if (M <= 64) {
    // ---- register fast path ----
    float s = -1.0f; int n = -1;
    if (lane < M) { s = ls[lane]; n = ln[lane]; }
    int rank = 0;
    for (int j = 0; j < M; ++j) {
      const float sj = __shfl(s, j);
      const int nj = __shfl(n, j);
      if (lane < M) rank += (sj > s) || (sj == s && nj < n);
    }
    if (lane < M) { ss2[rank] = s; sn2[rank] = n; }
    __syncthreads();

    float sc = 0.0f; int sn = 0;
    float x1 = 0.0f, y1 = 0.0f, x2 = 0.0f, y2 = 0.0f;
    if (lane < M) {
      sc = ss2[lane]; sn = sn2[lane];
      const int i = b * Nn + sn;
      const float4 pr = *(const float4*)(props + (size_t)i * 4);
      const float4 rg = *(const float4*)(reg + ((size_t)i * Cn + c) * 4);
      const float4 bx = decode_clip(pr, rg);
      x1 = bx.x; y1 = bx.y; x2 = bx.z; y2 = bx.w;
    }
    const float area = (x2 - x1 + 1.0f) * (y2 - y1 + 1.0f);

    unsigned long long live = (M >= 64) ? ~0ull : ((1ull << M) - 1ull);
    int i = 0;
    while (i < 64) {
      const unsigned long long rem = live & (~0ull << i);
      if (!rem) break;
      i = __ffsll(rem) - 1;
      const float ax1 = __shfl(x1, i), ay1 = __shfl(y1, i);
      const float ax2 = __shfl(x2, i), ay2 = __shfl(y2, i);
      const float aarea = (ax2 - ax1 + 1.0f) * (ay2 - ay1 + 1.0f);
      const float xx1 = fmaxf(ax1, x1), yy1 = fmaxf(ay1, y1);
      const float xx2 = fminf(ax2, x2), yy2 = fminf(ay2, y2);
      const float inter = fmaxf(xx2 - xx1 + 1.0f, 0.0f) * fmaxf(yy2 - yy1 + 1.0f, 0.0f);
      const float iou = inter / (aarea + area - inter);
      const bool sup = (lane > i) && (lane < M) && ((live >> lane) & 1ull) && (iou > NMS_T);
      live &= ~__ballot(sup);
      ++i;
    }
    // M <= 64 < TOPN: top-300 cap can't bind
    if (lane < M && ((live >> lane) & 1ull)) {
      const unsigned long long key =
          ((unsigned long long)__float_as_uint(sc) << 32) | (unsigned int)(Cn - c);
      atomicMax(&packed[(size_t)b * Nn + sn], key);
    }
  } else {
    // ---- exact LDS fallback (M > 64, improbable) ----
    for (int i0 = lane; i0 < M; i0 += 64) {
      const float si = ls[i0]; const int ni = ln[i0];
      int r = 0;
      for (int j = 0; j < M; ++j) {
        const float sj = ls[j]; const int nj = ln[j];
        r += (sj > si) || (sj == si && nj < ni);
      }
      fs[r] = si; fn[r] = ni;
    }
    __syncthreads();
    for (int i0 = lane; i0 < M; i0 += 64) {
      const int i = b * Nn + fn[i0];
      const float4 pr = *(const float4*)(props + (size_t)i * 4);
      const float4 rg = *(const float4*)(reg + ((size_t)i * Cn + c) * 4);
      const float4 bx = decode_clip(pr, rg);
      fb[i0][0] = bx.x; fb[i0][1] = bx.y; fb[i0][2] = bx.z; fb[i0][3] = bx.w;
      kp[i0] = 1;
    }
    __syncthreads();
    for (int i = 0; i < M; ++i) {
      if (!kp[i]) continue;                 // uniform: kp[i] stable here
      const float ax1 = fb[i][0], ay1 = fb[i][1], ax2 = fb[i][2], ay2 = fb[i][3];
      const float aarea = (ax2 - ax1 + 1.0f) * (ay2 - ay1 + 1.0f);
      for (int t = i + 1 + lane; t < M; t += 64) {
        if (kp[t]) {
          const float bx1 = fb[t][0], by1 = fb[t][1], bx2 = fb[t][2], by2 = fb[t][3];
          const float barea = (bx2 - bx1 + 1.0f) * (by2 - by1 + 1.0f);
          const float xx1 = fmaxf(ax1, bx1), yy1 = fmaxf(ay1, by1);
          const float xx2 = fminf(ax2, bx2), yy2 = fminf(ay2, by2);
          const float inter = fmaxf(xx2 - xx1 + 1.0f, 0.0f) * fmaxf(yy2 - yy1 + 1.0f, 0.0f);
          if (inter / (aarea + barea - inter) > NMS_T) kp[t] = 0;
        }
      }
      __syncthreads();
    }
    if (lane == 0) {
      int cnt = 0;
      for (int t = 0; t < M; ++t)
        if (kp[t]) { if (++cnt > TOPN) kp[t] = 0; }
    }
    __syncthreads();
    for (int t = lane; t < M; t += 64) {
      if (kp[t]) {
        const unsigned long long key =
            ((unsigned long long)__float_as_uint(fs[t]) << 32) | (unsigned int)(Cn - c);
        atomicMax(&packed[(size_t)b * Nn + fn[t]], key);
      }
    }
  }
}

// ---------------------------------------------------------------------------
// kC: one block per image (512 threads = 1 thread per proposal). Unpack
// (score,label), top-100 threshold (bitonic only when num>100), decode the
// winning-class box on demand, write boxes/scores/labels/valid outputs.
__global__ void kC_final(const unsigned long long* __restrict__ packed,
                         const float* __restrict__ reg,
                         const float* __restrict__ props,
                         float* __restrict__ out) {
  const int b = blockIdx.x;
  const int n = threadIdx.x;        // 0..511
  __shared__ float v[Nn];
  __shared__ int wcnt[8];
  __shared__ float sThr;

  const unsigned long long p = packed[(size_t)b * Nn + n];
  const float s = __uint_as_float((unsigned int)(p >> 32));
  const int label = (p != 0ull) ? (Cn - (int)(p & 0xFFFFFFFFull)) : 0;
  const bool pos = (s > 0.0f);
  v[n] = pos ? s : -1.0f;

  // count positives (wave ballots -> LDS)
  const unsigned long long bal = __ballot(pos);
  if ((n & 63) == 0) wcnt[n >> 6] = __popcll(bal);
  __syncthreads();
  int num = 0;
  #pragma unroll
  for (int i = 0; i < 8; ++i) num += wcnt[i];

  if (num > DETMAX) {
    // bitonic sort v descending (values only)
    for (int k = 2; k <= Nn; k <<= 1) {
      for (int j = k >> 1; j > 0; j >>= 1) {
        const int ixj = n ^ j;
        if (ixj > n) {
          const bool up = ((n & k) == 0);
          const float a = v[n], bb = v[ixj];
          if (up != (a > bb) && a != bb) { v[n] = bb; v[ixj] = a; }
        }
        __syncthreads();
      }
    }
    if (n == 0) sThr = v[DETMAX - 1];
  } else {
    if (n == 0) sThr = -1.0f;
  }
  __syncthreads();

  const bool valid = pos && (s >= sThr);
  const int i = b * Nn + n;
  float4 ob = make_float4(0.0f, 0.0f, 0.0f, 0.0f);
  if (valid) {
    const float4 pr = *(const float4*)(props + (size_t)i * 4);
    const float4 rg = *(const float4*)(reg + ((size_t)i * Cn + label) * 4);
    ob = decode_clip(pr, rg);
  }
  *(float4*)(out + OFF_BOXES + (size_t)i * 4) = ob;
  out[OFF_SCORES + i] = valid ? s : 0.0f;
  out[OFF_LABELS + i] = valid ? (float)label : 0.0f;
  out[OFF_VALID + i] = valid ? 1.0f : 0.0f;
}

// ---------------------------------------------------------------------------
// kD: nms_features = features * det_valid. grid = B*N rows, block = 256, float4.
__global__ void kD_feats(const float* __restrict__ feats,
                         const float* __restrict__ valid,
                         float* __restrict__ out) {
  const int row = blockIdx.x;
  const float m = valid[row];
  const float4* fi = (const float4*)(feats + (size_t)row * Dn);
  float4* fo = (float4*)(out + (size_t)row * Dn);
  #pragma unroll 4
  for (int t = threadIdx.x; t < Dn / 4; t += 256) {
    float4 x = fi[t];
    x.x *= m; x.y *= m; x.z *= m; x.w *= m;
    fo[t] = x;
  }
}

// ---------------------------------------------------------------------------
extern "C" void kernel_launch(void* const* d_in, const int* in_sizes, int n_in,
                              void* d_out, int out_size, void* d_ws, size_t ws_size,
                              hipStream_t stream) {
  const float* logits = (const float*)d_in[0];   // [B,N,C]
  const float* reg    = (const float*)d_in[1];   // [B,N,C*4]
  const float* props  = (const float*)d_in[2];   // [B,N,4]
  const float* feats  = (const float*)d_in[3];   // [B,N,D]
  float* out = (float*)d_out;

  // workspace carve-up: packed (8B-aligned, first), prob_t
  unsigned long long* packed = (unsigned long long*)d_ws;          // B*N
  float* prob_t = (float*)(packed + Bn * Nn);                      // B*C*N

  kA_softmax<<<Bn * Nn / 4, 256, 0, stream>>>(logits, prob_t, packed);
  kB_nms<<<Bn * Cn, 64, 0, stream>>>(prob_t, reg, props, packed);
  kC_final<<<Bn, Nn, 0, stream>>>(packed, reg, props, out);
  kD_feats<<<Bn * Nn, 256, 0, stream>>>(feats, out + OFF_VALID, out + OFF_FEATS);
}